// Round 6
// baseline (447.670 us; speedup 1.0000x reference)
//
#include <hip/hip_runtime.h>

// DiffeomorphicLearnerTorch, R11.
// R10 passed (absmax 0.015625) at 43.5us/launch — cvt_pk VALU diet didn't
// move dur; VALU count exonerated. New arithmetic: per block per tile 48KB
// of L2 reads (16KB Zj staging + 4 waves x 8KB ATf, where the two ig waves
// read IDENTICAL ATf frags -> 16KB duplicated). ~27k cyc/CU/launch of L2
// traffic + ~400cyc L2 latency on PV's operand loads = the dominant stall.
// R11: stage each tile's 16 ATf frags (16KB, both dh halves) into LDS once
// per block (global_load_lds, 4 frags/wave), double-buffered; PV reads them
// via ds_read_b128 just-in-time (lane-stride 16B = 2-way bank alias, free).
// Halves ATf L2 traffic, converts PV operand latency L2->LDS, removes the
// bw reg hoist from the S-chain window. LDS 64KB/block -> 2 blocks/CU kept.
// Math identical to R10 (verified).
// Structure: per-wave S^T = mfma(A=Zj_lds, B=Zi_regs), P lane-local,
// cvt_pk+permlane32_swap feeds PV directly; one barrier per 32-j tile.
// Wave = 32 i-rows x 128 d-cols; block = 4 waves; grid (8 chunks, 64
// i-blocks) = 512 blocks.
// Frag-linear layouts (verified R4/R5):
//   Zf  [128 jblk][16 ks][64 lane]x8 bf16
//   ATf [t][8 dblk][256 jb][64 lane]x8 bf16
// eperm = erow permuted to S^T reg order (pidx).

#define N_PTS 4096
#define DIM   256
#define DT_C  0.125f
#define C1    (1.0f/512.0f)
#define C2    (1.0f/256.0f)

typedef __bf16 bf16x8 __attribute__((ext_vector_type(8)));
typedef float  f32x16 __attribute__((ext_vector_type(16)));
typedef float  f32x4v __attribute__((ext_vector_type(4)));
typedef unsigned int   u32x4 __attribute__((ext_vector_type(4)));
typedef unsigned short u16x8 __attribute__((ext_vector_type(8)));

__device__ __forceinline__ unsigned short f2bf(float f) {
  unsigned int u = __builtin_bit_cast(unsigned int, f);
  u += 0x7fffu + ((u >> 16) & 1u);          // RNE
  return (unsigned short)(u >> 16);
}
__device__ __forceinline__ float bf2f(unsigned short s) {
  unsigned int u = ((unsigned int)s) << 16;
  return __builtin_bit_cast(float, u);
}

typedef __attribute__((address_space(1))) const unsigned int gas_u32;
typedef __attribute__((address_space(3))) unsigned int las_u32;
__device__ __forceinline__ void gload_lds16(const void* g, void* l) {
  __builtin_amdgcn_global_load_lds((gas_u32*)g, (las_u32*)l, 16, 0, 0);
}

// ---- ATf: A[t][4096][256] f32 -> frag-linear bf16 B-operand tiles ----
__global__ __launch_bounds__(256) void k_prep(const float* __restrict__ A,
                                              unsigned short* __restrict__ ATf) {
  __shared__ float sT[64][36];
  const int jgrp = blockIdx.x, ds = blockIdx.y, t = blockIdx.z;
  const int tid = threadIdx.x;
  const float* Ab = A + (size_t)t * N_PTS * DIM;
  {
    const int j_l = tid >> 2, dq = tid & 3;
    const float* src = Ab + (size_t)(jgrp * 64 + j_l) * DIM + ds * 32 + dq * 8;
    f32x4v v0 = *(const f32x4v*)src, v1 = *(const f32x4v*)(src + 4);
    *(f32x4v*)&sT[j_l][dq * 8] = v0;
    *(f32x4v*)&sT[j_l][dq * 8 + 4] = v1;
  }
  __syncthreads();
  const int jb_l = tid >> 6, l = tid & 63, l31 = l & 31, lhi = l >> 5;
  u16x8 o;
#pragma unroll
  for (int e = 0; e < 8; ++e) o[e] = f2bf(sT[jb_l * 16 + lhi * 8 + e][l31]);
  unsigned short* dst = ATf + (size_t)t * (8 * 256 * 64 * 8)
                      + ((size_t)(ds * 256 + jgrp * 4 + jb_l) * 64 + l) * 8;
  *(u16x8*)dst = o;
}

// eperm index for row r
__device__ __forceinline__ int pidx(int r) {
  const int jj = r & 31;
  return (r & ~31) | (((jj >> 2) & 1) << 4) | (((jj >> 3) & 3) << 2) | (jj & 3);
}

// ---- init: X -> Zf frags + erow + eperm ----
__global__ __launch_bounds__(256) void k_init(const float* __restrict__ X,
                                              unsigned short* __restrict__ Zf,
                                              float* __restrict__ erow,
                                              float* __restrict__ eperm) {
  const int tid = threadIdx.x;
  const int r = blockIdx.x * 8 + (tid >> 5), o = tid & 31;
  const size_t base = (size_t)r * DIM + o * 8;
  f32x4v z0 = *(const f32x4v*)(X + base), z1 = *(const f32x4v*)(X + base + 4);
  u16x8 zb; float s = 0.f;
#pragma unroll
  for (int i = 0; i < 4; ++i) { zb[i] = f2bf(z0[i]); zb[4 + i] = f2bf(z1[i]);
                                s += z0[i] * z0[i] + z1[i] * z1[i]; }
  *(u16x8*)(Zf + ((size_t)((r >> 5) * 16 + (o >> 1)) * 64 + (o & 1) * 32 + (r & 31)) * 8) = zb;
#pragma unroll
  for (int d = 16; d > 0; d >>= 1) s += __shfl_down(s, d, 32);
  if (o == 0) { const float e = __expf(-s * C1); erow[r] = e; eperm[pidx(r)] = e; }
}

// ---- fused flash, R11 ----
// grid (8 chunks, 64 i-blocks), 256 thr = 4 waves: ig=wid>>1 (32 i-rows),
// dh=wid&1 (128 d-cols). Zi resident in VGPRs (static indices only).
// Zj AND ATf double-buffered in LDS (16KB/tile each, global_load_lds).
// One barrier/tile.
__global__ __launch_bounds__(256, 2) void k_flash(
    const unsigned short* __restrict__ Zf, const float* __restrict__ erow,
    const float* __restrict__ eperm,
    const unsigned short* __restrict__ ATf_t,
    const float* __restrict__ Aaff_t,
    unsigned short* __restrict__ Opart) {
  __shared__ __align__(16) unsigned short sZj[2][16 * 64 * 8];  // 2 x 16KB
  __shared__ __align__(16) unsigned short sAT[2][16 * 64 * 8];  // 2 x 16KB

  const int tid = threadIdx.x, lane = tid & 63, wid = tid >> 6;
  const int l31 = lane & 31, lhi = lane >> 5;
  const int ig = wid >> 1, dh = wid & 1;
  const int chunk = blockIdx.x;
  const int i0 = blockIdx.y * 64;

  // stage tile 0: Zj (16KB: 4 x 16B per thread) + ATf (16 frags, 4 per wave)
  {
    const unsigned short* src = Zf + (size_t)(chunk * 16) * 8192;
#pragma unroll
    for (int p = 0; p < 4; ++p)
      gload_lds16(src + (size_t)(p * 256 + tid) * 8, &sZj[0][(p * 256 + tid) * 8]);
#pragma unroll
    for (int ff = 0; ff < 4; ++ff) {
      const int f = wid * 4 + ff;   // frag f = (dblk = f>>1, q = f&1)
      gload_lds16(ATf_t + ((size_t)((f >> 1) * 256 + chunk * 32 + (f & 1)) * 64 + lane) * 8,
                  &sAT[0][((size_t)f * 64 + lane) * 8]);
    }
  }

  // resident Zi frags: wave's 32 i-rows x K=256 (static indices ONLY)
  const unsigned short* zib = Zf + (size_t)(blockIdx.y * 2 + ig) * 8192;
  u32x4 zi[16];
#pragma unroll
  for (int ks = 0; ks < 16; ++ks)
    zi[ks] = *(const u32x4*)(zib + (size_t)ks * 512 + lane * 8);

  const float eI = erow[i0 + ig * 32 + l31];

  // O init + affine slice (ksg = chunk*2+q, unscaled; summed across chunks).
  // a-frag re-read from GLOBAL: zi[runtime] would demote zi[] to scratch (R7).
  f32x16 O[4];
#pragma unroll
  for (int ct = 0; ct < 4; ++ct)
#pragma unroll
    for (int i = 0; i < 16; ++i) O[ct][i] = 0.f;
#pragma unroll
  for (int q = 0; q < 2; ++q) {
    const int ksg = chunk * 2 + q;
    const bf16x8 a = *(const bf16x8*)(zib + (size_t)ksg * 512 + lane * 8);
#pragma unroll
    for (int ct = 0; ct < 4; ++ct) {
      const int d = dh * 128 + ct * 32 + l31;
      const float* bp = Aaff_t + (size_t)d * DIM + ksg * 16 + lhi * 8;
      f32x4v f0 = *(const f32x4v*)bp, f1 = *(const f32x4v*)(bp + 4);
      u16x8 tb;
#pragma unroll
      for (int i = 0; i < 4; ++i) { tb[i] = f2bf(f0[i]); tb[4 + i] = f2bf(f1[i]); }
      O[ct] = __builtin_amdgcn_mfma_f32_32x32x16_bf16(
          a, __builtin_bit_cast(bf16x8, tb), O[ct], 0, 0, 0);
    }
  }
  __syncthreads();

  const float* epc = eperm + (size_t)chunk * 512 + lhi * 16;

  for (int n = 0; n < 16; ++n) {
    const int cur = n & 1;
    // prefetch next tile (Zj + ATf) into other buffers — overlaps this
    // tile's compute; vmcnt drained by the end-of-iteration barrier.
    if (n < 15) {
      const unsigned short* src = Zf + (size_t)(chunk * 16 + n + 1) * 8192;
#pragma unroll
      for (int p = 0; p < 4; ++p)
        gload_lds16(src + (size_t)(p * 256 + tid) * 8,
                    &sZj[cur ^ 1][(p * 256 + tid) * 8]);
#pragma unroll
      for (int ff = 0; ff < 4; ++ff) {
        const int f = wid * 4 + ff;
        gload_lds16(ATf_t + ((size_t)((f >> 1) * 256 + chunk * 32 + (n + 1) * 2 + (f & 1)) * 64 + lane) * 8,
                    &sAT[cur ^ 1][((size_t)f * 64 + lane) * 8]);
      }
    }
    // ej hoist (16 regs; eperm is 16KB total — L1-hot)
    f32x4v e0 = *(const f32x4v*)(epc + n * 32);
    f32x4v e1 = *(const f32x4v*)(epc + n * 32 + 4);
    f32x4v e2 = *(const f32x4v*)(epc + n * 32 + 8);
    f32x4v e3 = *(const f32x4v*)(epc + n * 32 + 12);

    // S^T = Zj @ Zi^T : A=Zj (LDS), B=Zi (regs); 2 chains to halve dep depth
    f32x16 Sa, Sb;
#pragma unroll
    for (int i = 0; i < 16; ++i) { Sa[i] = 0.f; Sb[i] = 0.f; }
    __builtin_amdgcn_s_setprio(1);
#pragma unroll
    for (int ks = 0; ks < 16; ks += 2) {
      bf16x8 a0 = *(const bf16x8*)(&sZj[cur][(ks + 0) * 512 + lane * 8]);
      bf16x8 a1 = *(const bf16x8*)(&sZj[cur][(ks + 1) * 512 + lane * 8]);
      Sa = __builtin_amdgcn_mfma_f32_32x32x16_bf16(
          a0, __builtin_bit_cast(bf16x8, zi[ks + 0]), Sa, 0, 0, 0);
      Sb = __builtin_amdgcn_mfma_f32_32x32x16_bf16(
          a1, __builtin_bit_cast(bf16x8, zi[ks + 1]), Sb, 0, 0, 0);
    }
    __builtin_amdgcn_s_setprio(0);

    // PV b-frags from sAT[cur] (staged last iter): ds_read_b128, lane-stride
    // 16B (2-way bank alias = free). Issued here so lgkm latency hides
    // under the exp/pack VALU below.
    u32x4 bw0[4], bw1[4];
#pragma unroll
    for (int ct = 0; ct < 4; ++ct) {
      bw0[ct] = *(const u32x4*)(&sAT[cur][(((size_t)(dh * 4 + ct) * 2 + 0) * 64 + lane) * 8]);
      bw1[ct] = *(const u32x4*)(&sAT[cur][(((size_t)(dh * 4 + ct) * 2 + 1) * 64 + lane) * 8]);
    }

    // P^T: lane=(i,lhi), reg c -> j = n*32 + (c&3)+8*(c>>2)+4*lhi.
    // R8-verified math (eI*ej*expf), R7-verified cvt_pk pack.
    float p[16];
#pragma unroll
    for (int c = 0; c < 16; ++c) {
      const float ej = (c < 4) ? e0[c] : (c < 8) ? e1[c - 4]
                     : (c < 12) ? e2[c - 8] : e3[c - 12];
      p[c] = eI * ej * __expf((Sa[c] + Sb[c]) * C2);
    }
    unsigned int dw[4][2];
#pragma unroll
    for (int g = 0; g < 4; ++g) {
      asm("v_cvt_pk_bf16_f32 %0, %1, %2" : "=v"(dw[g][0]) : "v"(p[4 * g + 0]), "v"(p[4 * g + 1]));
      asm("v_cvt_pk_bf16_f32 %0, %1, %2" : "=v"(dw[g][1]) : "v"(p[4 * g + 2]), "v"(p[4 * g + 3]));
    }
    // permlane32_swap: x_new={x_lo,y_lo} -> frag words (e0..3), y_new -> (e4..7)
    {
      auto r0 = __builtin_amdgcn_permlane32_swap(dw[0][0], dw[1][0], false, false);
      auto r1 = __builtin_amdgcn_permlane32_swap(dw[0][1], dw[1][1], false, false);
      u32x4 paw; paw[0] = r0[0]; paw[1] = r1[0]; paw[2] = r0[1]; paw[3] = r1[1];
      const bf16x8 pa = __builtin_bit_cast(bf16x8, paw);
      __builtin_amdgcn_s_setprio(1);
#pragma unroll
      for (int ct = 0; ct < 4; ++ct)
        O[ct] = __builtin_amdgcn_mfma_f32_32x32x16_bf16(
            pa, __builtin_bit_cast(bf16x8, bw0[ct]), O[ct], 0, 0, 0);
      __builtin_amdgcn_s_setprio(0);
    }
    {
      auto r0 = __builtin_amdgcn_permlane32_swap(dw[2][0], dw[3][0], false, false);
      auto r1 = __builtin_amdgcn_permlane32_swap(dw[2][1], dw[3][1], false, false);
      u32x4 paw; paw[0] = r0[0]; paw[1] = r1[0]; paw[2] = r0[1]; paw[3] = r1[1];
      const bf16x8 pa = __builtin_bit_cast(bf16x8, paw);
      __builtin_amdgcn_s_setprio(1);
#pragma unroll
      for (int ct = 0; ct < 4; ++ct)
        O[ct] = __builtin_amdgcn_mfma_f32_32x32x16_bf16(
            pa, __builtin_bit_cast(bf16x8, bw1[ct]), O[ct], 0, 0, 0);
      __builtin_amdgcn_s_setprio(0);
    }
    __syncthreads();  // next tile staged (vmcnt drain) + all reads of cur done
  }

  // epilogue -> Opart[chunk] bf16 (P already carries ei*ej)
  unsigned short* ob = Opart + (size_t)chunk * N_PTS * DIM
                     + (size_t)(i0 + ig * 32) * DIM + dh * 128 + l31;
#pragma unroll
  for (int ct = 0; ct < 4; ++ct)
#pragma unroll
    for (int c = 0; c < 16; ++c) {
      const int row = 4 * lhi + (c & 3) + 8 * (c >> 2);
      ob[(size_t)row * DIM + ct * 32] = f2bf(O[ct][c]);
    }
}

// ---- update: Z += DT*(sum partials + baff); emit Zf frags + erow + eperm ----
__global__ __launch_bounds__(256) void k_update(const float* __restrict__ Zin,
                                                const unsigned short* __restrict__ Opart,
                                                const float* __restrict__ baff_t,
                                                float* __restrict__ Zout,
                                                unsigned short* __restrict__ Zf,
                                                float* __restrict__ erow,
                                                float* __restrict__ eperm) {
  const int tid = threadIdx.x;
  const int r = blockIdx.x * 8 + (tid >> 5), o = tid & 31;
  const size_t base = (size_t)r * DIM + o * 8;
  f32x4v z0 = *(const f32x4v*)(Zin + base), z1 = *(const f32x4v*)(Zin + base + 4);
  f32x4v s0 = *(const f32x4v*)(baff_t + o * 8), s1 = *(const f32x4v*)(baff_t + o * 8 + 4);
#pragma unroll
  for (int c = 0; c < 8; ++c) {
    u16x8 p = *(const u16x8*)(Opart + (size_t)c * N_PTS * DIM + base);
#pragma unroll
    for (int i = 0; i < 4; ++i) { s0[i] += bf2f(p[i]); s1[i] += bf2f(p[4 + i]); }
  }
  u16x8 zb; float sv = 0.f;
#pragma unroll
  for (int i = 0; i < 4; ++i) {
    z0[i] += DT_C * s0[i]; z1[i] += DT_C * s1[i];
    zb[i] = f2bf(z0[i]); zb[4 + i] = f2bf(z1[i]);
    sv += z0[i] * z0[i] + z1[i] * z1[i];
  }
  *(f32x4v*)(Zout + base) = z0;
  *(f32x4v*)(Zout + base + 4) = z1;
  *(u16x8*)(Zf + ((size_t)((r >> 5) * 16 + (o >> 1)) * 64 + (o & 1) * 32 + (r & 31)) * 8) = zb;
#pragma unroll
  for (int d = 16; d > 0; d >>= 1) sv += __shfl_down(sv, d, 32);
  if (o == 0) { const float e = __expf(-sv * C1); erow[r] = e; eperm[pidx(r)] = e; }
}

extern "C" void kernel_launch(void* const* d_in, const int* in_sizes, int n_in,
                              void* d_out, int out_size, void* d_ws, size_t ws_size,
                              hipStream_t stream) {
  const float* X    = (const float*)d_in[0];
  const float* A    = (const float*)d_in[1];
  const float* Aaff = (const float*)d_in[2];
  const float* baff = (const float*)d_in[3];
  float* out = (float*)d_out;

  char* w = (char*)d_ws;
  size_t off = 0;
  unsigned short* ATf = (unsigned short*)(w + off); off += (size_t)8 * 8 * 256 * 64 * 8 * 2; // 16 MiB
  unsigned short* Zf  = (unsigned short*)(w + off); off += (size_t)N_PTS * DIM * 2;          // 2 MiB
  float* erow  = (float*)(w + off); off += (size_t)N_PTS * 4;
  float* eperm = (float*)(w + off); off += (size_t)N_PTS * 4;
  float* Zf32 = (float*)(w + off); off += (size_t)N_PTS * DIM * 4;                           // 4 MiB
  unsigned short* Opart = (unsigned short*)(w + off); off += (size_t)8 * N_PTS * DIM * 2;    // 16 MiB
  (void)ws_size; (void)in_sizes; (void)n_in; (void)out_size;

  k_prep<<<dim3(64, 8, 8), 256, 0, stream>>>(A, ATf);
  k_init<<<512, 256, 0, stream>>>(X, Zf, erow, eperm);

  const float* zin = X;
  for (int t = 0; t < 8; ++t) {
    float* zout = (t == 7) ? out : Zf32;  // in-place safe after t=0
    k_flash<<<dim3(8, 64), 256, 0, stream>>>(
        Zf, erow, eperm, ATf + (size_t)t * (8 * 256 * 64 * 8), Aaff + (size_t)t * DIM * DIM, Opart);
    k_update<<<512, 256, 0, stream>>>(zin, Opart, baff + (size_t)t * DIM, zout, Zf, erow, eperm);
    zin = zout;
  }
}

// Round 7
// 437.578 us; speedup vs baseline: 1.0231x; 1.0231x over previous
//
#include <hip/hip_runtime.h>

// DiffeomorphicLearnerTorch, R12.
// Model reconciliation (R8-R11 counters): MfmaUtil 24% == 2 waves/SIMD x 392
// MFMA x 32cyc / 104k wall; VALUBusy==MfmaUtil in every run => fallback
// formula includes MFMA, real VALU ~1-2% (why R10's VALU diet was neutral).
// R11 neutral => L2 path exonerated. Remaining suspect: the 2-phase loop
// itself (m233: stage+vmcnt(0)+barrier = ~72% overhead regardless of phase
// content). Our __syncthreads per tile drains vmcnt to 0 -> staging pipeline
// never deeper than 1 tile -> exposed L2/L3 latency every tile.
// R12 (T3/T4 minimum form): Zj staging 4-deep (64KB/block, 2 blocks/CU),
// prefetch distance 2; ONE raw s_barrier per tile preceded by counted
// s_waitcnt vmcnt(20) (keeps stage(n+1),stage(n+2),bw/ej(n) in flight —
// never drains). bw/ej issued BEFORE stage(n+2) so the compiler's PV wait
// counts only stage(n+2) => vmcnt(4), no drain. Depth-4 ring: all
// concurrent LDS write/read pairs differ by 3 mod 4 (safe under the
// one-barrier-per-tile skew window). sAT dropped (R11 neutral).
// Math identical to R10 (verified, absmax 0.015625).
// Frag-linear layouts (verified R4/R5):
//   Zf  [128 jblk][16 ks][64 lane]x8 bf16
//   ATf [t][8 dblk][256 jb][64 lane]x8 bf16
// eperm = erow permuted to S^T reg order (pidx).

#define N_PTS 4096
#define DIM   256
#define DT_C  0.125f
#define C1    (1.0f/512.0f)
#define C2    (1.0f/256.0f)

typedef __bf16 bf16x8 __attribute__((ext_vector_type(8)));
typedef float  f32x16 __attribute__((ext_vector_type(16)));
typedef float  f32x4v __attribute__((ext_vector_type(4)));
typedef unsigned int   u32x4 __attribute__((ext_vector_type(4)));
typedef unsigned short u16x8 __attribute__((ext_vector_type(8)));

__device__ __forceinline__ unsigned short f2bf(float f) {
  unsigned int u = __builtin_bit_cast(unsigned int, f);
  u += 0x7fffu + ((u >> 16) & 1u);          // RNE
  return (unsigned short)(u >> 16);
}
__device__ __forceinline__ float bf2f(unsigned short s) {
  unsigned int u = ((unsigned int)s) << 16;
  return __builtin_bit_cast(float, u);
}

typedef __attribute__((address_space(1))) const unsigned int gas_u32;
typedef __attribute__((address_space(3))) unsigned int las_u32;
__device__ __forceinline__ void gload_lds16(const void* g, void* l) {
  __builtin_amdgcn_global_load_lds((gas_u32*)g, (las_u32*)l, 16, 0, 0);
}

// ---- ATf: A[t][4096][256] f32 -> frag-linear bf16 B-operand tiles ----
__global__ __launch_bounds__(256) void k_prep(const float* __restrict__ A,
                                              unsigned short* __restrict__ ATf) {
  __shared__ float sT[64][36];
  const int jgrp = blockIdx.x, ds = blockIdx.y, t = blockIdx.z;
  const int tid = threadIdx.x;
  const float* Ab = A + (size_t)t * N_PTS * DIM;
  {
    const int j_l = tid >> 2, dq = tid & 3;
    const float* src = Ab + (size_t)(jgrp * 64 + j_l) * DIM + ds * 32 + dq * 8;
    f32x4v v0 = *(const f32x4v*)src, v1 = *(const f32x4v*)(src + 4);
    *(f32x4v*)&sT[j_l][dq * 8] = v0;
    *(f32x4v*)&sT[j_l][dq * 8 + 4] = v1;
  }
  __syncthreads();
  const int jb_l = tid >> 6, l = tid & 63, l31 = l & 31, lhi = l >> 5;
  u16x8 o;
#pragma unroll
  for (int e = 0; e < 8; ++e) o[e] = f2bf(sT[jb_l * 16 + lhi * 8 + e][l31]);
  unsigned short* dst = ATf + (size_t)t * (8 * 256 * 64 * 8)
                      + ((size_t)(ds * 256 + jgrp * 4 + jb_l) * 64 + l) * 8;
  *(u16x8*)dst = o;
}

// eperm index for row r
__device__ __forceinline__ int pidx(int r) {
  const int jj = r & 31;
  return (r & ~31) | (((jj >> 2) & 1) << 4) | (((jj >> 3) & 3) << 2) | (jj & 3);
}

// ---- init: X -> Zf frags + erow + eperm ----
__global__ __launch_bounds__(256) void k_init(const float* __restrict__ X,
                                              unsigned short* __restrict__ Zf,
                                              float* __restrict__ erow,
                                              float* __restrict__ eperm) {
  const int tid = threadIdx.x;
  const int r = blockIdx.x * 8 + (tid >> 5), o = tid & 31;
  const size_t base = (size_t)r * DIM + o * 8;
  f32x4v z0 = *(const f32x4v*)(X + base), z1 = *(const f32x4v*)(X + base + 4);
  u16x8 zb; float s = 0.f;
#pragma unroll
  for (int i = 0; i < 4; ++i) { zb[i] = f2bf(z0[i]); zb[4 + i] = f2bf(z1[i]);
                                s += z0[i] * z0[i] + z1[i] * z1[i]; }
  *(u16x8*)(Zf + ((size_t)((r >> 5) * 16 + (o >> 1)) * 64 + (o & 1) * 32 + (r & 31)) * 8) = zb;
#pragma unroll
  for (int d = 16; d > 0; d >>= 1) s += __shfl_down(s, d, 32);
  if (o == 0) { const float e = __expf(-s * C1); erow[r] = e; eperm[pidx(r)] = e; }
}

// ---- fused flash, R12: counted-vmcnt pipeline, 4-deep Zj ring ----
// grid (8 chunks, 64 i-blocks), 256 thr = 4 waves: ig=wid>>1 (32 i-rows),
// dh=wid&1 (128 d-cols). Zi resident in VGPRs (static indices only).
__global__ __launch_bounds__(256, 2) void k_flash(
    const unsigned short* __restrict__ Zf, const float* __restrict__ erow,
    const float* __restrict__ eperm,
    const unsigned short* __restrict__ ATf_t,
    const float* __restrict__ Aaff_t,
    unsigned short* __restrict__ Opart) {
  __shared__ __align__(16) unsigned short sZj[4][16 * 64 * 8];  // 4 x 16KB ring

  const int tid = threadIdx.x, lane = tid & 63, wid = tid >> 6;
  const int l31 = lane & 31, lhi = lane >> 5;
  const int ig = wid >> 1, dh = wid & 1;
  const int chunk = blockIdx.x;
  const int i0 = blockIdx.y * 64;

  // prologue: stage tiles 0 and 1 (max lead time: issue before anything else)
#pragma unroll
  for (int pre = 0; pre < 2; ++pre) {
    const unsigned short* src = Zf + (size_t)(chunk * 16 + pre) * 8192;
#pragma unroll
    for (int p = 0; p < 4; ++p)
      gload_lds16(src + (size_t)(p * 256 + tid) * 8,
                  &sZj[pre][(p * 256 + tid) * 8]);
  }

  // resident Zi frags: wave's 32 i-rows x K=256 (static indices ONLY)
  const unsigned short* zib = Zf + (size_t)(blockIdx.y * 2 + ig) * 8192;
  u32x4 zi[16];
#pragma unroll
  for (int ks = 0; ks < 16; ++ks)
    zi[ks] = *(const u32x4*)(zib + (size_t)ks * 512 + lane * 8);

  const float eI = erow[i0 + ig * 32 + l31];

  // O init + affine slice (ksg = chunk*2+q, unscaled; summed across chunks).
  // a-frag re-read from GLOBAL: zi[runtime] would demote zi[] to scratch (R7).
  f32x16 O[4];
#pragma unroll
  for (int ct = 0; ct < 4; ++ct)
#pragma unroll
    for (int i = 0; i < 16; ++i) O[ct][i] = 0.f;
#pragma unroll
  for (int q = 0; q < 2; ++q) {
    const int ksg = chunk * 2 + q;
    const bf16x8 a = *(const bf16x8*)(zib + (size_t)ksg * 512 + lane * 8);
#pragma unroll
    for (int ct = 0; ct < 4; ++ct) {
      const int d = dh * 128 + ct * 32 + l31;
      const float* bp = Aaff_t + (size_t)d * DIM + ksg * 16 + lhi * 8;
      f32x4v f0 = *(const f32x4v*)bp, f1 = *(const f32x4v*)(bp + 4);
      u16x8 tb;
#pragma unroll
      for (int i = 0; i < 4; ++i) { tb[i] = f2bf(f0[i]); tb[4 + i] = f2bf(f1[i]); }
      O[ct] = __builtin_amdgcn_mfma_f32_32x32x16_bf16(
          a, __builtin_bit_cast(bf16x8, tb), O[ct], 0, 0, 0);
    }
  }

  const float* epc = eperm + (size_t)chunk * 512 + lhi * 16;
  const unsigned short* atb =
      ATf_t + ((size_t)(dh * 4 * 256 + chunk * 32) * 64 + lane) * 8;

  for (int n = 0; n < 16; ++n) {
    const int cur = n & 3;
    // ---- pre-barrier: operand loads for tile n, THEN stage tile n+2 ----
    // (bw/ej issued before the stage so the compiler's PV wait counts only
    //  stage(n+2) -> vmcnt(4), leaving the staging pipeline in flight.)
    f32x4v e0 = *(const f32x4v*)(epc + n * 32);
    f32x4v e1 = *(const f32x4v*)(epc + n * 32 + 4);
    f32x4v e2 = *(const f32x4v*)(epc + n * 32 + 8);
    f32x4v e3 = *(const f32x4v*)(epc + n * 32 + 12);
    u32x4 bw0[4], bw1[4];
#pragma unroll
    for (int ct = 0; ct < 4; ++ct) {
      bw0[ct] = *(const u32x4*)(atb + ((size_t)ct * 256 + n * 2 + 0) * 512);
      bw1[ct] = *(const u32x4*)(atb + ((size_t)ct * 256 + n * 2 + 1) * 512);
    }
    if (n < 14) {
      const unsigned short* src = Zf + (size_t)(chunk * 16 + n + 2) * 8192;
#pragma unroll
      for (int p = 0; p < 4; ++p)
        gload_lds16(src + (size_t)(p * 256 + tid) * 8,
                    &sZj[(n + 2) & 3][(p * 256 + tid) * 8]);
    }
    // counted wait: allow stage(n+1)4 + bw/ej(n)12 + stage(n+2)4 = 20 to stay
    // outstanding; everything older (incl. stage(n)) forced complete.
    asm volatile("s_waitcnt vmcnt(20)" ::: "memory");
    __builtin_amdgcn_sched_barrier(0);
    __builtin_amdgcn_s_barrier();
    __builtin_amdgcn_sched_barrier(0);

    // ---- compute tile n from sZj[cur] ----
    // S^T = Zj @ Zi^T : A=Zj (LDS), B=Zi (regs); 2 chains to halve dep depth
    f32x16 Sa, Sb;
#pragma unroll
    for (int i = 0; i < 16; ++i) { Sa[i] = 0.f; Sb[i] = 0.f; }
    __builtin_amdgcn_s_setprio(1);
#pragma unroll
    for (int ks = 0; ks < 16; ks += 2) {
      bf16x8 a0 = *(const bf16x8*)(&sZj[cur][(ks + 0) * 512 + lane * 8]);
      bf16x8 a1 = *(const bf16x8*)(&sZj[cur][(ks + 1) * 512 + lane * 8]);
      Sa = __builtin_amdgcn_mfma_f32_32x32x16_bf16(
          a0, __builtin_bit_cast(bf16x8, zi[ks + 0]), Sa, 0, 0, 0);
      Sb = __builtin_amdgcn_mfma_f32_32x32x16_bf16(
          a1, __builtin_bit_cast(bf16x8, zi[ks + 1]), Sb, 0, 0, 0);
    }
    __builtin_amdgcn_s_setprio(0);

    // P^T: lane=(i,lhi), reg c -> j = n*32 + (c&3)+8*(c>>2)+4*lhi.
    // R8-verified math (eI*ej*expf), R7-verified cvt_pk pack.
    float p[16];
#pragma unroll
    for (int c = 0; c < 16; ++c) {
      const float ej = (c < 4) ? e0[c] : (c < 8) ? e1[c - 4]
                     : (c < 12) ? e2[c - 8] : e3[c - 12];
      p[c] = eI * ej * __expf((Sa[c] + Sb[c]) * C2);
    }
    unsigned int dw[4][2];
#pragma unroll
    for (int g = 0; g < 4; ++g) {
      asm("v_cvt_pk_bf16_f32 %0, %1, %2" : "=v"(dw[g][0]) : "v"(p[4 * g + 0]), "v"(p[4 * g + 1]));
      asm("v_cvt_pk_bf16_f32 %0, %1, %2" : "=v"(dw[g][1]) : "v"(p[4 * g + 2]), "v"(p[4 * g + 3]));
    }
    // permlane32_swap: x_new={x_lo,y_lo} -> frag words (e0..3), y_new -> (e4..7)
    {
      auto r0 = __builtin_amdgcn_permlane32_swap(dw[0][0], dw[1][0], false, false);
      auto r1 = __builtin_amdgcn_permlane32_swap(dw[0][1], dw[1][1], false, false);
      u32x4 paw; paw[0] = r0[0]; paw[1] = r1[0]; paw[2] = r0[1]; paw[3] = r1[1];
      const bf16x8 pa = __builtin_bit_cast(bf16x8, paw);
      __builtin_amdgcn_s_setprio(1);
#pragma unroll
      for (int ct = 0; ct < 4; ++ct)
        O[ct] = __builtin_amdgcn_mfma_f32_32x32x16_bf16(
            pa, __builtin_bit_cast(bf16x8, bw0[ct]), O[ct], 0, 0, 0);
      __builtin_amdgcn_s_setprio(0);
    }
    {
      auto r0 = __builtin_amdgcn_permlane32_swap(dw[2][0], dw[3][0], false, false);
      auto r1 = __builtin_amdgcn_permlane32_swap(dw[2][1], dw[3][1], false, false);
      u32x4 paw; paw[0] = r0[0]; paw[1] = r1[0]; paw[2] = r0[1]; paw[3] = r1[1];
      const bf16x8 pa = __builtin_bit_cast(bf16x8, paw);
      __builtin_amdgcn_s_setprio(1);
#pragma unroll
      for (int ct = 0; ct < 4; ++ct)
        O[ct] = __builtin_amdgcn_mfma_f32_32x32x16_bf16(
            pa, __builtin_bit_cast(bf16x8, bw1[ct]), O[ct], 0, 0, 0);
      __builtin_amdgcn_s_setprio(0);
    }
    // no end-of-iter barrier: next iter's counted vmcnt + s_barrier gates
    // tile n+1; depth-4 ring keeps concurrent write/read buffers disjoint.
  }

  // epilogue -> Opart[chunk] bf16 (P already carries ei*ej)
  unsigned short* ob = Opart + (size_t)chunk * N_PTS * DIM
                     + (size_t)(i0 + ig * 32) * DIM + dh * 128 + l31;
#pragma unroll
  for (int ct = 0; ct < 4; ++ct)
#pragma unroll
    for (int c = 0; c < 16; ++c) {
      const int row = 4 * lhi + (c & 3) + 8 * (c >> 2);
      ob[(size_t)row * DIM + ct * 32] = f2bf(O[ct][c]);
    }
}

// ---- update: Z += DT*(sum partials + baff); emit Zf frags + erow + eperm ----
__global__ __launch_bounds__(256) void k_update(const float* __restrict__ Zin,
                                                const unsigned short* __restrict__ Opart,
                                                const float* __restrict__ baff_t,
                                                float* __restrict__ Zout,
                                                unsigned short* __restrict__ Zf,
                                                float* __restrict__ erow,
                                                float* __restrict__ eperm) {
  const int tid = threadIdx.x;
  const int r = blockIdx.x * 8 + (tid >> 5), o = tid & 31;
  const size_t base = (size_t)r * DIM + o * 8;
  f32x4v z0 = *(const f32x4v*)(Zin + base), z1 = *(const f32x4v*)(Zin + base + 4);
  f32x4v s0 = *(const f32x4v*)(baff_t + o * 8), s1 = *(const f32x4v*)(baff_t + o * 8 + 4);
#pragma unroll
  for (int c = 0; c < 8; ++c) {
    u16x8 p = *(const u16x8*)(Opart + (size_t)c * N_PTS * DIM + base);
#pragma unroll
    for (int i = 0; i < 4; ++i) { s0[i] += bf2f(p[i]); s1[i] += bf2f(p[4 + i]); }
  }
  u16x8 zb; float sv = 0.f;
#pragma unroll
  for (int i = 0; i < 4; ++i) {
    z0[i] += DT_C * s0[i]; z1[i] += DT_C * s1[i];
    zb[i] = f2bf(z0[i]); zb[4 + i] = f2bf(z1[i]);
    sv += z0[i] * z0[i] + z1[i] * z1[i];
  }
  *(f32x4v*)(Zout + base) = z0;
  *(f32x4v*)(Zout + base + 4) = z1;
  *(u16x8*)(Zf + ((size_t)((r >> 5) * 16 + (o >> 1)) * 64 + (o & 1) * 32 + (r & 31)) * 8) = zb;
#pragma unroll
  for (int d = 16; d > 0; d >>= 1) sv += __shfl_down(sv, d, 32);
  if (o == 0) { const float e = __expf(-sv * C1); erow[r] = e; eperm[pidx(r)] = e; }
}

extern "C" void kernel_launch(void* const* d_in, const int* in_sizes, int n_in,
                              void* d_out, int out_size, void* d_ws, size_t ws_size,
                              hipStream_t stream) {
  const float* X    = (const float*)d_in[0];
  const float* A    = (const float*)d_in[1];
  const float* Aaff = (const float*)d_in[2];
  const float* baff = (const float*)d_in[3];
  float* out = (float*)d_out;

  char* w = (char*)d_ws;
  size_t off = 0;
  unsigned short* ATf = (unsigned short*)(w + off); off += (size_t)8 * 8 * 256 * 64 * 8 * 2; // 16 MiB
  unsigned short* Zf  = (unsigned short*)(w + off); off += (size_t)N_PTS * DIM * 2;          // 2 MiB
  float* erow  = (float*)(w + off); off += (size_t)N_PTS * 4;
  float* eperm = (float*)(w + off); off += (size_t)N_PTS * 4;
  float* Zf32 = (float*)(w + off); off += (size_t)N_PTS * DIM * 4;                           // 4 MiB
  unsigned short* Opart = (unsigned short*)(w + off); off += (size_t)8 * N_PTS * DIM * 2;    // 16 MiB
  (void)ws_size; (void)in_sizes; (void)n_in; (void)out_size;

  k_prep<<<dim3(64, 8, 8), 256, 0, stream>>>(A, ATf);
  k_init<<<512, 256, 0, stream>>>(X, Zf, erow, eperm);

  const float* zin = X;
  for (int t = 0; t < 8; ++t) {
    float* zout = (t == 7) ? out : Zf32;  // in-place safe after t=0
    k_flash<<<dim3(8, 64), 256, 0, stream>>>(
        Zf, erow, eperm, ATf + (size_t)t * (8 * 256 * 64 * 8), Aaff + (size_t)t * DIM * DIM, Opart);
    k_update<<<512, 256, 0, stream>>>(zin, Opart, baff + (size_t)t * DIM, zout, Zf, erow, eperm);
    zin = zout;
  }
}